// Round 3
// baseline (265.447 us; speedup 1.0000x reference)
//
#include <hip/hip_runtime.h>
#include <math.h>

// Problem constants (match reference)
#define B_    4
#define T_    2048
#define D_    1024
#define F_    4096
#define R_    (B_*T_)      // 8192 rows (b,t)
#define SEG_  64           // segments per time-chain
#define L_    (T_/SEG_)    // 32 steps per segment
#define DECAYF 0.9f
#define OMDF   0.1f        // 1 - decay
// Flag threshold below 0.5: the k4 fallback re-tests at exactly 0.5 in fp32,
// so flags only need NO FALSE NEGATIVES. fp8(x8-scaled) GEMM error is
// ~1e-3 RMS (6-sigma ~7e-3); margin 0.05 is ~7x worst plausible error.
#define FLAG_THRESH 0.45f

typedef __attribute__((ext_vector_type(4)))  int   i32x4;
typedef __attribute__((ext_vector_type(8)))  int   i32x8;
typedef __attribute__((ext_vector_type(16))) float f32x16;

// pack 4 floats into 4 fp8 e4m3 bytes (byte0 = first arg)
__device__ __forceinline__ int pk_fp8x4(float x, float y, float z, float w) {
    int p = 0;
    p = __builtin_amdgcn_cvt_pk_fp8_f32(x, y, p, false);  // bytes 0,1
    p = __builtin_amdgcn_cvt_pk_fp8_f32(z, w, p, true);   // bytes 2,3
    return p;
}

// ---------------------------------------------------------------------------
// PACKED OPERAND LAYOUT (R9): emit fp8 arrays in MFMA-operand tile order so
// k2 needs NO LDS at all:
//   panel P = row>>5 (32 rows), k-chunk C = kbyte>>6 (64 B) -> 2 KB tile at
//   byte ((P*16 + C) * 2048). Within a tile, byte  h*1024 + l*16 + t  holds
//   element [row = P*32 + (l&31)][k = C*64 + (l>>5)*32 + h*16 + t].
// A wave's 32x32x64 fragment load = two 1 KB contiguous global_load_dwordx4
// (lane l at l*16, halves at +0/+1024) — perfectly coalesced, straight to
// VGPRs, zero LDS, zero barriers.
__device__ __forceinline__ size_t pk_off(int row, int d) {
    // byte offset of element [row][d] in the packed layout
    return ((size_t)((row >> 5) * 16 + (d >> 6)) * 2048)
         + ((d >> 4) & 1) * 1024
         + ((row & 31) + ((d >> 5) & 1) * 32) * 16
         + (d & 15);
}

// ---------------------------------------------------------------------------
// KA: fused prologue. Grid-partitioned roles:
//   blocks [0, 4096):       W1 fp32 -> fp8 e4m3 x8, packed operand layout
//   blocks [4096, 4352):    per-segment EMA end-state (seg_sum)
//   blocks [4352, 4384):    zero the 8192 per-row spike flags
#define KA_W1_BLOCKS  4096
#define KA_SEG_BLOCKS 256
#define KA_FLAG_BLOCKS 32

__global__ __launch_bounds__(256)
void kA_prologue(const float* __restrict__ spikes,
                 const float* __restrict__ W1,
                 unsigned char* __restrict__ w_f8,
                 float* __restrict__ seg_sum,
                 unsigned int* __restrict__ flags) {
    const int bid = blockIdx.x;
    const int tid = threadIdx.x;
    if (bid < KA_W1_BLOCKS) {
        int i = bid * 256 + tid;                  // float4 index over W1 [F x D]
        float4 v = ((const float4*)W1)[i];
        int f  = i >> 8;                          // D/4 = 256 groups per row
        int d0 = (i & 255) * 4;
        *(int*)(w_f8 + pk_off(f, d0)) = pk_fp8x4(8.f*v.x, 8.f*v.y, 8.f*v.z, 8.f*v.w);
    } else if (bid < KA_W1_BLOCKS + KA_SEG_BLOCKS) {
        int t = (bid - KA_W1_BLOCKS) * 256 + tid; // B_*SEG_*D_/4 threads
        int dg = t & (D_ / 4 - 1);
        int s = (t >> 8) & (SEG_ - 1);
        int b = t >> 14;
        const float4* sp4 = (const float4*)spikes;
        const int base = (b * T_ + s * L_) * (D_ / 4) + dg;
        float4 e = {0.f, 0.f, 0.f, 0.f};
#pragma unroll 8
        for (int k = 0; k < L_; ++k) {
            float4 x = sp4[base + k * (D_ / 4)];
            e.x = DECAYF * e.x + OMDF * x.x;
            e.y = DECAYF * e.y + OMDF * x.y;
            e.z = DECAYF * e.z + OMDF * x.z;
            e.w = DECAYF * e.w + OMDF * x.w;
        }
        ((float4*)seg_sum)[(b * SEG_ + s) * (D_ / 4) + dg] = e;
    } else {
        int i = (bid - KA_W1_BLOCKS - KA_SEG_BLOCKS) * 256 + tid;
        if (i < R_) flags[i] = 0u;
    }
}

// ---------------------------------------------------------------------------
// KC (R12: kB fused in): per (b,s) block, first compute the segment start
// state directly as the weighted sum over PRIOR segments' end-states
//   start(s) = sum_{j<s} W^(s-1-j) * seg_sum[j],   W = 0.9^32
// (serial forward loop, block-uniform trip count s, seg_sum is 1 MB and
// L2-resident — replaces the kB launch). Then the segment-local EMA + fp8
// pack as before; start_state is written out for k4's exact slow path.
__global__ __launch_bounds__(256)
void kC_scan_ema_fp8(const float* __restrict__ spikes,
                     const float* __restrict__ seg_sum,
                     float* __restrict__ start_state,
                     unsigned char* __restrict__ a_f8) {
    int t = blockIdx.x * 256 + threadIdx.x;            // B_*SEG_*D_/4 threads
    int dg = t & (D_ / 4 - 1);
    int s = (t >> 8) & (SEG_ - 1);                     // block-uniform
    int b = t >> 14;

    // ---- fused kB: weighted scan over prior segments (exact same math:
    // the EMA recurrence is linear, so seg-start state = decayed sum of
    // prior segment end-state contributions).
    const float4* ss4 = (const float4*)seg_sum;
    const float W = 0.0343368382f;                     // 0.9^32
    float4 e = {0.f, 0.f, 0.f, 0.f};
    for (int j = 0; j < s; ++j) {                      // uniform trip count
        float4 g = ss4[(b * SEG_ + j) * (D_ / 4) + dg];
        e.x = W * e.x + g.x;
        e.y = W * e.y + g.y;
        e.z = W * e.z + g.z;
        e.w = W * e.w + g.w;
    }
    ((float4*)start_state)[(b * SEG_ + s) * (D_ / 4) + dg] = e;

    // ---- segment-local EMA + fp8 pack (unchanged)
    const float4* sp4 = (const float4*)spikes;
    const int base = (b * T_ + s * L_) * (D_ / 4) + dg;
    const int d0 = dg * 4;
    unsigned char* dst = a_f8 + pk_off(b * T_ + s * L_, d0);   // k=0 element
#pragma unroll 8
    for (int k = 0; k < L_; ++k) {
        float4 x = sp4[base + k * (D_ / 4)];
        e.x = DECAYF * e.x + OMDF * x.x;
        e.y = DECAYF * e.y + OMDF * x.y;
        e.z = DECAYF * e.z + OMDF * x.z;
        e.w = DECAYF * e.w + OMDF * x.w;
        *(int*)(dst + k * 16) = pk_fp8x4(8.f*e.x, 8.f*e.y, 8.f*e.z, 8.f*e.w);
    }
}

// ---------------------------------------------------------------------------
// K2: MX-fp8 32x32x64 streaming GEMM, NO LDS, NO BARRIERS.
// R12 model revision: k2 is L2-BANDWIDTH-bound, not latency-bound.
// R1 measured 44 us == 1 GB L2 traffic (2048 blocks x 512 KB, 2x wave-pair
// redundancy on both operands) / ~23 TB/s achievable L2. So: cut traffic.
// Per-wave tile 64x64 -> 64x128 (block 128x256, 4 waves 2m x 2n, acc[2][4]):
// FLOP/L2-byte 64 -> 85, total traffic 1 GB -> 768 MB. Load structure stays
// the compiler-scheduled no-asm form that passed in R1 (R2's asm-opaque
// pipeline crashed; latency depth wasn't the limiter anyway).
// XCD swizzle: 1024 blocks, 128/XCD as 16m x 8n chunk = A 2 MB + B 2 MB =
// exactly one XCD's L2; n-fast so the A-panel stays hot across 8 blocks.
// NOTE: plain __launch_bounds__(256). R5's (256,3) floor spilled the
// accumulators to scratch. Never floor-cap this kernel.
// VGPR: acc 128 + frags ~48 + addr -> ~200 expected, 2 waves/SIMD. If
// VGPR_Count >= 256 or scratch WRITE_SIZE appears, shrink to acc[2][3].
__global__ __launch_bounds__(256)
void k2_mfma_flags(const unsigned char* __restrict__ Ap,  // packed a_f8
                   const unsigned char* __restrict__ Bp,  // packed w_f8
                   unsigned int* __restrict__ flags) {
    const int tid = threadIdx.x;
    const int w = tid >> 6;
    const int lane = tid & 63;
    // XCD-chunked swizzle: 1024 blocks, 8 XCDs, 128 blocks/XCD as 16m x 8n.
    // Bijective: xcd = ((mt>>4)<<1)|(nt>>3), id = (mt&15)*8 + (nt&7).
    const int orig = blockIdx.x;
    const int xcd  = orig & 7;
    const int id   = orig >> 3;                     // 0..127 within XCD
    const int mt   = (xcd >> 1) * 16 + (id >> 3);   // 0..63 (m-tile)
    const int nt   = (xcd & 1) * 8 + (id & 7);      // 0..15 (n-tile, fast)
    const int m0 = mt * 128;
    const int n0 = nt * 256;
    const int wm = w >> 1, wn = w & 1;
    const int kg = lane >> 5;

    // Per-lane stream base pointers: 6 operand streams (2 A, 4 B panels).
    // Panel P's 16 k-tiles are contiguous (32 KB); iter C reads at +C*2048.
    const unsigned char* pA0 = Ap + ((size_t)((m0 >> 5) + wm * 2 + 0) * 16) * 2048 + lane * 16;
    const unsigned char* pA1 = Ap + ((size_t)((m0 >> 5) + wm * 2 + 1) * 16) * 2048 + lane * 16;
    const unsigned char* pB0 = Bp + ((size_t)((n0 >> 5) + wn * 4 + 0) * 16) * 2048 + lane * 16;
    const unsigned char* pB1 = Bp + ((size_t)((n0 >> 5) + wn * 4 + 1) * 16) * 2048 + lane * 16;
    const unsigned char* pB2 = Bp + ((size_t)((n0 >> 5) + wn * 4 + 2) * 16) * 2048 + lane * 16;
    const unsigned char* pB3 = Bp + ((size_t)((n0 >> 5) + wn * 4 + 3) * 16) * 2048 + lane * 16;

    f32x16 acc[2][4] = {};

#define LDFRAG(p, C)                                                        \
    ({ i32x4 lo_ = *(const i32x4*)((p) + (size_t)(C) * 2048);               \
       i32x4 hi_ = *(const i32x4*)((p) + (size_t)(C) * 2048 + 1024);        \
       (i32x8){lo_.x, lo_.y, lo_.z, lo_.w, hi_.x, hi_.y, hi_.z, hi_.w}; })

#define MFMA1(i, j, AF, BF)                                                 \
    acc[i][j] = __builtin_amdgcn_mfma_scale_f32_32x32x64_f8f6f4(            \
        AF, BF, acc[i][j], 0, 0, 0, 124, 0, 124);

#pragma unroll
    for (int C = 0; C < 16; ++C) {
        i32x8 A0 = LDFRAG(pA0, C), A1 = LDFRAG(pA1, C);
        i32x8 B0 = LDFRAG(pB0, C), B1 = LDFRAG(pB1, C);
        i32x8 B2 = LDFRAG(pB2, C), B3 = LDFRAG(pB3, C);
        MFMA1(0, 0, A0, B0) MFMA1(0, 1, A0, B1)
        MFMA1(0, 2, A0, B2) MFMA1(0, 3, A0, B3)
        MFMA1(1, 0, A1, B0) MFMA1(1, 1, A1, B1)
        MFMA1(1, 2, A1, B2) MFMA1(1, 3, A1, B3)
    }
#undef LDFRAG
#undef MFMA1

    // Epilogue: per-row spike flags. 32x32 C/D layout (m74/m101-verified):
    // col = lane&31, row = (reg&3) + 8*(reg>>2) + 4*(lane>>5).
#pragma unroll
    for (int i = 0; i < 2; ++i) {
#pragma unroll
        for (int reg = 0; reg < 16; ++reg) {
            float mx = fmaxf(fmaxf(acc[i][0][reg], acc[i][1][reg]),
                             fmaxf(acc[i][2][reg], acc[i][3][reg]));
            if (mx > FLAG_THRESH) {
                const int rr = (reg & 3) + 8 * (reg >> 2) + 4 * kg;
                atomicOr(&flags[m0 + wm * 64 + i * 32 + rr], 1u);
            }
        }
    }
}

// ---------------------------------------------------------------------------
// K4: one block per (b,t) row. Unflagged rows (the overwhelmingly common
// case) write zeros. Flagged rows take the exact fp32 slow path, rebuilding
// the EMA row from start_state + <=32 spike rows.
__global__ __launch_bounds__(256)
void k4_output(const float* __restrict__ spikes,
               const float* __restrict__ start_state,
               const float* __restrict__ W1,
               const float* __restrict__ Wr,
               const float* __restrict__ W2,
               const unsigned int* __restrict__ flags,
               float* __restrict__ out) {
    const int row = blockIdx.x;          // 0..R_-1
    const int tid = threadIdx.x;
    float4 o = {0.f, 0.f, 0.f, 0.f};

    if (flags[row] == 0u) {              // wave-uniform branch (per block)
        *(float4*)&out[(size_t)row * D_ + tid * 4] = o;
        return;
    }

    __shared__ float se[D_];
    __shared__ float sp[D_];
    __shared__ float red[256];
    __shared__ int nspk;
    __shared__ int spk_list[256];

    const int b = row / T_;
    const int t = row % T_;
    const int seg = t / L_;
    const int off = t % L_;
    const int segbase = (b * T_ + seg * L_) * D_;

    for (int i = tid; i < D_; i += 256) {
        float e = start_state[(b * SEG_ + seg) * D_ + i];
        for (int j = 0; j <= off; ++j)
            e = DECAYF * e + OMDF * spikes[segbase + j * D_ + i];
        se[i] = e;
        sp[i] = spikes[(size_t)row * D_ + i];
    }
    if (tid == 0) nspk = 0;
    __syncthreads();

    for (int f0 = 0; f0 < F_; f0 += 256) {
        int f = f0 + tid;
        float mix = 0.f;
        for (int k = 0; k < D_; ++k) mix += se[k] * W1[(size_t)f * D_ + k];
        if (mix > 0.5f) {
            int idx = atomicAdd(&nspk, 1);
            spk_list[idx] = f;
        }
        __syncthreads();
        int n = nspk;
        for (int i = 0; i < n; ++i) {
            int fs = spk_list[i];
            float part = 0.f;
#pragma unroll
            for (int k = 0; k < 4; ++k)
                part += sp[tid * 4 + k] * Wr[(size_t)fs * D_ + tid * 4 + k];
            red[tid] = part;
            __syncthreads();
            for (int sft = 128; sft > 0; sft >>= 1) {
                if (tid < sft) red[tid] += red[tid + sft];
                __syncthreads();
            }
            float r = 1.f / (1.f + expf(-red[0]));
            __syncthreads();
            o.x += r * W2[(size_t)(tid * 4 + 0) * F_ + fs];
            o.y += r * W2[(size_t)(tid * 4 + 1) * F_ + fs];
            o.z += r * W2[(size_t)(tid * 4 + 2) * F_ + fs];
            o.w += r * W2[(size_t)(tid * 4 + 3) * F_ + fs];
        }
        __syncthreads();
        if (tid == 0) nspk = 0;
        __syncthreads();
    }
    *(float4*)&out[(size_t)row * D_ + tid * 4] = o;
}

// ---------------------------------------------------------------------------
extern "C" void kernel_launch(void* const* d_in, const int* in_sizes, int n_in,
                              void* d_out, int out_size, void* d_ws, size_t ws_size,
                              hipStream_t stream) {
    const float* spikes = (const float*)d_in[0];   // [B,T,D]
    const float* W1     = (const float*)d_in[1];   // [F,D]
    const float* W2     = (const float*)d_in[2];   // [D,F]
    const float* Wr     = (const float*)d_in[3];   // [F,D]
    float* out = (float*)d_out;                    // [B,T,D]

    // workspace layout (~14.3 MB total)
    char* ws = (char*)d_ws;
    float* seg_sum      = (float*)ws;                                // 1 MB
    float* start_state  = seg_sum + (size_t)B_ * SEG_ * D_;          // 1 MB
    unsigned int* flags = (unsigned int*)(start_state + (size_t)B_ * SEG_ * D_); // 32 KB
    unsigned char* a_f8 = (unsigned char*)(flags + R_);              // 8 MB, packed
    unsigned char* w_f8 = a_f8 + (size_t)R_ * D_;                    // 4 MB, packed

    kA_prologue<<<KA_W1_BLOCKS + KA_SEG_BLOCKS + KA_FLAG_BLOCKS, 256, 0, stream>>>(
        spikes, W1, w_f8, seg_sum, flags);

    // kB fused into kC (R12)
    kC_scan_ema_fp8<<<(B_ * SEG_ * D_ / 4) / 256, 256, 0, stream>>>(
        spikes, seg_sum, start_state, a_f8);

    // 128x256 block tile -> 1024 blocks
    k2_mfma_flags<<<(R_ / 128) * (F_ / 256), 256, 0, stream>>>(a_f8, w_f8, flags);

    k4_output<<<R_, 256, 0, stream>>>(spikes, start_state, W1, Wr, W2, flags, out);
}

// Round 4
// 202.937 us; speedup vs baseline: 1.3080x; 1.3080x over previous
//
#include <hip/hip_runtime.h>
#include <math.h>

// Problem constants (match reference)
#define B_    4
#define T_    2048
#define D_    1024
#define F_    4096
#define R_    (B_*T_)      // 8192 rows (b,t)
#define SEG_  64           // segments per time-chain
#define L_    (T_/SEG_)    // 32 steps per segment
#define DECAYF 0.9f
#define OMDF   0.1f        // 1 - decay
// Flag threshold below 0.5: the k4 fallback re-tests at exactly 0.5 in fp32,
// so flags only need NO FALSE NEGATIVES. fp8(x8-scaled) GEMM error is
// ~1e-3 RMS (6-sigma ~7e-3); margin 0.05 is ~7x worst plausible error.
#define FLAG_THRESH 0.45f

typedef __attribute__((ext_vector_type(4)))  int   i32x4;
typedef __attribute__((ext_vector_type(8)))  int   i32x8;
typedef __attribute__((ext_vector_type(16))) float f32x16;

// pack 4 floats into 4 fp8 e4m3 bytes (byte0 = first arg)
__device__ __forceinline__ int pk_fp8x4(float x, float y, float z, float w) {
    int p = 0;
    p = __builtin_amdgcn_cvt_pk_fp8_f32(x, y, p, false);  // bytes 0,1
    p = __builtin_amdgcn_cvt_pk_fp8_f32(z, w, p, true);   // bytes 2,3
    return p;
}

// ---------------------------------------------------------------------------
// PACKED OPERAND LAYOUT (R9): emit fp8 arrays in MFMA-operand tile order so
// k2 needs NO LDS at all:
//   panel P = row>>5 (32 rows), k-chunk C = kbyte>>6 (64 B) -> 2 KB tile at
//   byte ((P*16 + C) * 2048). Within a tile, byte  h*1024 + l*16 + t  holds
//   element [row = P*32 + (l&31)][k = C*64 + (l>>5)*32 + h*16 + t].
// A wave's 32x32x64 fragment load = two 1 KB contiguous global_load_dwordx4
// (lane l at l*16, halves at +0/+1024) — perfectly coalesced, straight to
// VGPRs, zero LDS, zero barriers.
__device__ __forceinline__ size_t pk_off(int row, int d) {
    // byte offset of element [row][d] in the packed layout
    return ((size_t)((row >> 5) * 16 + (d >> 6)) * 2048)
         + ((d >> 4) & 1) * 1024
         + ((row & 31) + ((d >> 5) & 1) * 32) * 16
         + (d & 15);
}

// ---------------------------------------------------------------------------
// KA: fused prologue. Grid-partitioned roles:
//   blocks [0, 4096):       W1 fp32 -> fp8 e4m3 x8, packed operand layout
//   blocks [4096, 4352):    per-segment EMA end-state (seg_sum)
//   blocks [4352, 4384):    zero the 8192 per-row spike flags
#define KA_W1_BLOCKS  4096
#define KA_SEG_BLOCKS 256
#define KA_FLAG_BLOCKS 32

__global__ __launch_bounds__(256)
void kA_prologue(const float* __restrict__ spikes,
                 const float* __restrict__ W1,
                 unsigned char* __restrict__ w_f8,
                 float* __restrict__ seg_sum,
                 unsigned int* __restrict__ flags) {
    const int bid = blockIdx.x;
    const int tid = threadIdx.x;
    if (bid < KA_W1_BLOCKS) {
        int i = bid * 256 + tid;                  // float4 index over W1 [F x D]
        float4 v = ((const float4*)W1)[i];
        int f  = i >> 8;                          // D/4 = 256 groups per row
        int d0 = (i & 255) * 4;
        *(int*)(w_f8 + pk_off(f, d0)) = pk_fp8x4(8.f*v.x, 8.f*v.y, 8.f*v.z, 8.f*v.w);
    } else if (bid < KA_W1_BLOCKS + KA_SEG_BLOCKS) {
        int t = (bid - KA_W1_BLOCKS) * 256 + tid; // B_*SEG_*D_/4 threads
        int dg = t & (D_ / 4 - 1);
        int s = (t >> 8) & (SEG_ - 1);
        int b = t >> 14;
        const float4* sp4 = (const float4*)spikes;
        const int base = (b * T_ + s * L_) * (D_ / 4) + dg;
        float4 e = {0.f, 0.f, 0.f, 0.f};
#pragma unroll 8
        for (int k = 0; k < L_; ++k) {
            float4 x = sp4[base + k * (D_ / 4)];
            e.x = DECAYF * e.x + OMDF * x.x;
            e.y = DECAYF * e.y + OMDF * x.y;
            e.z = DECAYF * e.z + OMDF * x.z;
            e.w = DECAYF * e.w + OMDF * x.w;
        }
        ((float4*)seg_sum)[(b * SEG_ + s) * (D_ / 4) + dg] = e;
    } else {
        int i = (bid - KA_W1_BLOCKS - KA_SEG_BLOCKS) * 256 + tid;
        if (i < R_) flags[i] = 0u;
    }
}

// ---------------------------------------------------------------------------
// KB: weighted Kogge-Stone scan over the 64 segments of each (b,d) chain,
// one chain per 64-lane wave (lane = segment). start_state[s] = scan[s-1].
// (R4: restored — R3's serial-scan fusion into kC was ~15 us slower.)
__global__ __launch_bounds__(256)
void kB_seg_scan(const float* __restrict__ seg_sum,
                 float* __restrict__ start_state) {
    int g = blockIdx.x * 256 + threadIdx.x;   // B_*D_*64 threads
    int s = g & 63;                           // segment = lane
    int c = g >> 6;                           // chain id: 0..B_*D_-1
    int d = c & (D_ - 1);
    int b = c >> 10;
    int idx = (b * SEG_ + s) * D_ + d;
    float v = seg_sum[idx];
    float wp = 0.0343368382f;                 // 0.9^32 (per-segment decay)
#pragma unroll
    for (int off = 1; off < SEG_; off <<= 1) {
        float u = __shfl_up(v, off, 64);
        if (s >= off) v += wp * u;
        wp *= wp;                             // w^1, w^2, w^4, ...
    }
    float pv = __shfl_up(v, 1, 64);
    start_state[idx] = (s == 0) ? 0.f : pv;
}

// ---------------------------------------------------------------------------
// KC: recompute segment-local EMA seeded with start_state; emit fp8 (x8)
// into the packed operand layout.
__global__ __launch_bounds__(256)
void kC_ema_fp8(const float* __restrict__ spikes,
                const float* __restrict__ start_state,
                unsigned char* __restrict__ a_f8) {
    int t = blockIdx.x * 256 + threadIdx.x;            // B_*SEG_*D_/4 threads
    int dg = t & (D_ / 4 - 1);
    int s = (t >> 8) & (SEG_ - 1);
    int b = t >> 14;
    const float4* sp4 = (const float4*)spikes;
    const int base = (b * T_ + s * L_) * (D_ / 4) + dg;
    const int d0 = dg * 4;
    unsigned char* dst = a_f8 + pk_off(b * T_ + s * L_, d0);   // k=0 element
    float4 e = ((const float4*)start_state)[(b * SEG_ + s) * (D_ / 4) + dg];
#pragma unroll 8
    for (int k = 0; k < L_; ++k) {
        float4 x = sp4[base + k * (D_ / 4)];
        e.x = DECAYF * e.x + OMDF * x.x;
        e.y = DECAYF * e.y + OMDF * x.y;
        e.z = DECAYF * e.z + OMDF * x.z;
        e.w = DECAYF * e.w + OMDF * x.w;
        *(int*)(dst + k * 16) = pk_fp8x4(8.f*e.x, 8.f*e.y, 8.f*e.z, 8.f*e.w);
    }
}

// ---------------------------------------------------------------------------
// K2: MX-fp8 32x32x64 streaming GEMM, NO LDS. R4: back to the R1-verified
// 128x128 / acc[2][2] shape (R3's acc[2][4] spilled: VGPR=256, 256 MB
// scratch; R2's asm pipeline crashed — neither is revisited).
// Model: L2-BW-bound. Per block the 4 waves read 512 KB from L2 (every tile
// fetched by 2 waves), x2048 blocks = 1 GB / ~23 TB/s = the measured 44 us.
// The unique per-K-chunk working set is 16 KB (4 A-tiles + 4 B-tiles x
// 2 KB) — it FITS the 32 KB L1. The redundancy exists only because the 4
// waves drift across chunks and lines are evicted between the two readers.
// R4 change: LOCKSTEP the block — __syncthreads() + sched_barrier(0) at
// each K-chunk top. Both readers of a line now arrive within one chunk
// window -> L1 dedupes -> L2 traffic ~halves. Prediction: 44 -> ~30 us.
// Falsifier: if k2 >= 44 us, latency-bound (not L2-BW) -> remove barrier,
// go LDS B-staging next.
// NOTE: plain __launch_bounds__(256). Never floor-cap this kernel.
__global__ __launch_bounds__(256)
void k2_mfma_flags(const unsigned char* __restrict__ Ap,  // packed a_f8
                   const unsigned char* __restrict__ Bp,  // packed w_f8
                   unsigned int* __restrict__ flags) {
    const int tid = threadIdx.x;
    const int w = tid >> 6;
    const int lane = tid & 63;
    // XCD-chunked swizzle: 2048 blocks, 8 XCDs, 256 blocks/XCD as 16m x 16n.
    // Bijective since 2048 % 8 == 0.
    const int orig = blockIdx.x;
    const int xcd  = orig & 7;
    const int id   = orig >> 3;            // 0..255 within XCD
    const int mt   = (xcd >> 1) * 16 + (id >> 4);   // 0..63 (m-tile)
    const int nt   = (xcd & 1) * 16 + (id & 15);    // 0..31 (n-tile, fast)
    const int m0 = mt * 128;
    const int n0 = nt * 128;
    const int wm = w >> 1, wn = w & 1;
    const int kg = lane >> 5;

    // Per-lane stream base pointers: 4 operand streams (2 A tiles, 2 B tiles).
    // Panel P's 16 k-tiles are contiguous (32 KB); chunk C reads at +C*2048.
    const unsigned char* pa0 = Ap + ((size_t)((m0 >> 5) + wm * 2 + 0) * 16) * 2048 + lane * 16;
    const unsigned char* pa1 = Ap + ((size_t)((m0 >> 5) + wm * 2 + 1) * 16) * 2048 + lane * 16;
    const unsigned char* pb0 = Bp + ((size_t)((n0 >> 5) + wn * 2 + 0) * 16) * 2048 + lane * 16;
    const unsigned char* pb1 = Bp + ((size_t)((n0 >> 5) + wn * 2 + 1) * 16) * 2048 + lane * 16;

    f32x16 acc[2][2] = {};

#define LDFRAG(p, C)                                                        \
    ({ i32x4 lo_ = *(const i32x4*)((p) + (size_t)(C) * 2048);               \
       i32x4 hi_ = *(const i32x4*)((p) + (size_t)(C) * 2048 + 1024);        \
       (i32x8){lo_.x, lo_.y, lo_.z, lo_.w, hi_.x, hi_.y, hi_.z, hi_.w}; })

#define MFMA4(AF0, AF1, BF0, BF1)                                           \
    {                                                                       \
        acc[0][0] = __builtin_amdgcn_mfma_scale_f32_32x32x64_f8f6f4(        \
            AF0, BF0, acc[0][0], 0, 0, 0, 124, 0, 124);                     \
        acc[0][1] = __builtin_amdgcn_mfma_scale_f32_32x32x64_f8f6f4(        \
            AF0, BF1, acc[0][1], 0, 0, 0, 124, 0, 124);                     \
        acc[1][0] = __builtin_amdgcn_mfma_scale_f32_32x32x64_f8f6f4(        \
            AF1, BF0, acc[1][0], 0, 0, 0, 124, 0, 124);                     \
        acc[1][1] = __builtin_amdgcn_mfma_scale_f32_32x32x64_f8f6f4(        \
            AF1, BF1, acc[1][1], 0, 0, 0, 124, 0, 124);                     \
    }

#pragma unroll
    for (int C = 0; C < 16; ++C) {
        // Lockstep: all 4 waves enter chunk C together; fence so the loads
        // below cannot be hoisted above the barrier (keeps the 16 KB chunk
        // working set temporally dense -> L1 serves the second reader).
        __syncthreads();
        __builtin_amdgcn_sched_barrier(0);
        i32x8 A0 = LDFRAG(pa0, C), A1 = LDFRAG(pa1, C);
        i32x8 B0 = LDFRAG(pb0, C), B1 = LDFRAG(pb1, C);
        MFMA4(A0, A1, B0, B1);
    }
#undef LDFRAG
#undef MFMA4

    // Epilogue: per-row spike flags. 32x32 C/D layout (m74/m101-verified):
    // col = lane&31, row = (reg&3) + 8*(reg>>2) + 4*(lane>>5).
#pragma unroll
    for (int i = 0; i < 2; ++i) {
#pragma unroll
        for (int reg = 0; reg < 16; ++reg) {
            float mx = fmaxf(acc[i][0][reg], acc[i][1][reg]);
            if (mx > FLAG_THRESH) {
                const int rr = (reg & 3) + 8 * (reg >> 2) + 4 * kg;
                atomicOr(&flags[m0 + wm * 64 + i * 32 + rr], 1u);
            }
        }
    }
}

// ---------------------------------------------------------------------------
// K4: one block per (b,t) row. Unflagged rows (the overwhelmingly common
// case) write zeros. Flagged rows take the exact fp32 slow path, rebuilding
// the EMA row from start_state + <=32 spike rows.
__global__ __launch_bounds__(256)
void k4_output(const float* __restrict__ spikes,
               const float* __restrict__ start_state,
               const float* __restrict__ W1,
               const float* __restrict__ Wr,
               const float* __restrict__ W2,
               const unsigned int* __restrict__ flags,
               float* __restrict__ out) {
    const int row = blockIdx.x;          // 0..R_-1
    const int tid = threadIdx.x;
    float4 o = {0.f, 0.f, 0.f, 0.f};

    if (flags[row] == 0u) {              // wave-uniform branch (per block)
        *(float4*)&out[(size_t)row * D_ + tid * 4] = o;
        return;
    }

    __shared__ float se[D_];
    __shared__ float sp[D_];
    __shared__ float red[256];
    __shared__ int nspk;
    __shared__ int spk_list[256];

    const int b = row / T_;
    const int t = row % T_;
    const int seg = t / L_;
    const int off = t % L_;
    const int segbase = (b * T_ + seg * L_) * D_;

    for (int i = tid; i < D_; i += 256) {
        float e = start_state[(b * SEG_ + seg) * D_ + i];
        for (int j = 0; j <= off; ++j)
            e = DECAYF * e + OMDF * spikes[segbase + j * D_ + i];
        se[i] = e;
        sp[i] = spikes[(size_t)row * D_ + i];
    }
    if (tid == 0) nspk = 0;
    __syncthreads();

    for (int f0 = 0; f0 < F_; f0 += 256) {
        int f = f0 + tid;
        float mix = 0.f;
        for (int k = 0; k < D_; ++k) mix += se[k] * W1[(size_t)f * D_ + k];
        if (mix > 0.5f) {
            int idx = atomicAdd(&nspk, 1);
            spk_list[idx] = f;
        }
        __syncthreads();
        int n = nspk;
        for (int i = 0; i < n; ++i) {
            int fs = spk_list[i];
            float part = 0.f;
#pragma unroll
            for (int k = 0; k < 4; ++k)
                part += sp[tid * 4 + k] * Wr[(size_t)fs * D_ + tid * 4 + k];
            red[tid] = part;
            __syncthreads();
            for (int sft = 128; sft > 0; sft >>= 1) {
                if (tid < sft) red[tid] += red[tid + sft];
                __syncthreads();
            }
            float r = 1.f / (1.f + expf(-red[0]));
            __syncthreads();
            o.x += r * W2[(size_t)(tid * 4 + 0) * F_ + fs];
            o.y += r * W2[(size_t)(tid * 4 + 1) * F_ + fs];
            o.z += r * W2[(size_t)(tid * 4 + 2) * F_ + fs];
            o.w += r * W2[(size_t)(tid * 4 + 3) * F_ + fs];
        }
        __syncthreads();
        if (tid == 0) nspk = 0;
        __syncthreads();
    }
    *(float4*)&out[(size_t)row * D_ + tid * 4] = o;
}

// ---------------------------------------------------------------------------
extern "C" void kernel_launch(void* const* d_in, const int* in_sizes, int n_in,
                              void* d_out, int out_size, void* d_ws, size_t ws_size,
                              hipStream_t stream) {
    const float* spikes = (const float*)d_in[0];   // [B,T,D]
    const float* W1     = (const float*)d_in[1];   // [F,D]
    const float* W2     = (const float*)d_in[2];   // [D,F]
    const float* Wr     = (const float*)d_in[3];   // [F,D]
    float* out = (float*)d_out;                    // [B,T,D]

    // workspace layout (~14.3 MB total)
    char* ws = (char*)d_ws;
    float* seg_sum      = (float*)ws;                                // 1 MB
    float* start_state  = seg_sum + (size_t)B_ * SEG_ * D_;          // 1 MB
    unsigned int* flags = (unsigned int*)(start_state + (size_t)B_ * SEG_ * D_); // 32 KB
    unsigned char* a_f8 = (unsigned char*)(flags + R_);              // 8 MB, packed
    unsigned char* w_f8 = a_f8 + (size_t)R_ * D_;                    // 4 MB, packed

    kA_prologue<<<KA_W1_BLOCKS + KA_SEG_BLOCKS + KA_FLAG_BLOCKS, 256, 0, stream>>>(
        spikes, W1, w_f8, seg_sum, flags);
    kB_seg_scan<<<(B_ * D_ * 64) / 256, 256, 0, stream>>>(seg_sum, start_state);
    kC_ema_fp8<<<(B_ * SEG_ * D_ / 4) / 256, 256, 0, stream>>>(spikes, start_state, a_f8);

    k2_mfma_flags<<<(R_ / 128) * (F_ / 128), 256, 0, stream>>>(a_f8, w_f8, flags);

    k4_output<<<R_, 256, 0, stream>>>(spikes, start_state, W1, Wr, W2, flags, out);
}

// Round 5
// 183.685 us; speedup vs baseline: 1.4451x; 1.1048x over previous
//
#include <hip/hip_runtime.h>
#include <math.h>

// Problem constants (match reference)
#define B_    4
#define T_    2048
#define D_    1024
#define F_    4096
#define R_    (B_*T_)      // 8192 rows (b,t)
#define SEG_  64           // segments per time-chain
#define L_    (T_/SEG_)    // 32 steps per segment
#define DECAYF 0.9f
#define OMDF   0.1f        // 1 - decay
// Flag threshold below 0.5: the k4 fallback re-tests at exactly 0.5 in fp32,
// so flags only need NO FALSE NEGATIVES. fp8(x8-scaled) GEMM error is
// ~1e-3 RMS (6-sigma ~7e-3); margin 0.05 is ~7x worst plausible error.
#define FLAG_THRESH 0.45f

typedef __attribute__((ext_vector_type(4)))  int   i32x4;
typedef __attribute__((ext_vector_type(8)))  int   i32x8;
typedef __attribute__((ext_vector_type(16))) float f32x16;

// pack 4 floats into 4 fp8 e4m3 bytes (byte0 = first arg)
__device__ __forceinline__ int pk_fp8x4(float x, float y, float z, float w) {
    int p = 0;
    p = __builtin_amdgcn_cvt_pk_fp8_f32(x, y, p, false);  // bytes 0,1
    p = __builtin_amdgcn_cvt_pk_fp8_f32(z, w, p, true);   // bytes 2,3
    return p;
}

// ---------------------------------------------------------------------------
// PACKED OPERAND LAYOUT (R9): emit fp8 arrays in MFMA-operand tile order so
// k2 needs NO LDS at all:
//   panel P = row>>5 (32 rows), k-chunk C = kbyte>>6 (64 B) -> 2 KB tile at
//   byte ((P*16 + C) * 2048). Within a tile, byte  h*1024 + l*16 + t  holds
//   element [row = P*32 + (l&31)][k = C*64 + (l>>5)*32 + h*16 + t].
// A wave's 32x32x64 fragment load = two 1 KB contiguous global_load_dwordx4
// (lane l at l*16, halves at +0/+1024) — perfectly coalesced, straight to
// VGPRs, zero LDS, zero barriers.
__device__ __forceinline__ size_t pk_off(int row, int d) {
    // byte offset of element [row][d] in the packed layout
    return ((size_t)((row >> 5) * 16 + (d >> 6)) * 2048)
         + ((d >> 4) & 1) * 1024
         + ((row & 31) + ((d >> 5) & 1) * 32) * 16
         + (d & 15);
}

// ---------------------------------------------------------------------------
// KA: fused prologue. Grid-partitioned roles:
//   blocks [0, 4096):       W1 fp32 -> fp8 e4m3 x8, packed operand layout
//   blocks [4096, 4352):    per-segment EMA end-state (seg_sum)
//   blocks [4352, 4384):    zero the 8192 per-row spike flags
#define KA_W1_BLOCKS  4096
#define KA_SEG_BLOCKS 256
#define KA_FLAG_BLOCKS 32

__global__ __launch_bounds__(256)
void kA_prologue(const float* __restrict__ spikes,
                 const float* __restrict__ W1,
                 unsigned char* __restrict__ w_f8,
                 float* __restrict__ seg_sum,
                 unsigned int* __restrict__ flags) {
    const int bid = blockIdx.x;
    const int tid = threadIdx.x;
    if (bid < KA_W1_BLOCKS) {
        int i = bid * 256 + tid;                  // float4 index over W1 [F x D]
        float4 v = ((const float4*)W1)[i];
        int f  = i >> 8;                          // D/4 = 256 groups per row
        int d0 = (i & 255) * 4;
        *(int*)(w_f8 + pk_off(f, d0)) = pk_fp8x4(8.f*v.x, 8.f*v.y, 8.f*v.z, 8.f*v.w);
    } else if (bid < KA_W1_BLOCKS + KA_SEG_BLOCKS) {
        int t = (bid - KA_W1_BLOCKS) * 256 + tid; // B_*SEG_*D_/4 threads
        int dg = t & (D_ / 4 - 1);
        int s = (t >> 8) & (SEG_ - 1);
        int b = t >> 14;
        const float4* sp4 = (const float4*)spikes;
        const int base = (b * T_ + s * L_) * (D_ / 4) + dg;
        float4 e = {0.f, 0.f, 0.f, 0.f};
#pragma unroll 8
        for (int k = 0; k < L_; ++k) {
            float4 x = sp4[base + k * (D_ / 4)];
            e.x = DECAYF * e.x + OMDF * x.x;
            e.y = DECAYF * e.y + OMDF * x.y;
            e.z = DECAYF * e.z + OMDF * x.z;
            e.w = DECAYF * e.w + OMDF * x.w;
        }
        ((float4*)seg_sum)[(b * SEG_ + s) * (D_ / 4) + dg] = e;
    } else {
        int i = (bid - KA_W1_BLOCKS - KA_SEG_BLOCKS) * 256 + tid;
        if (i < R_) flags[i] = 0u;
    }
}

// ---------------------------------------------------------------------------
// KB: weighted Kogge-Stone scan over the 64 segments of each (b,d) chain,
// one chain per 64-lane wave (lane = segment). start_state[s] = scan[s-1].
__global__ __launch_bounds__(256)
void kB_seg_scan(const float* __restrict__ seg_sum,
                 float* __restrict__ start_state) {
    int g = blockIdx.x * 256 + threadIdx.x;   // B_*D_*64 threads
    int s = g & 63;                           // segment = lane
    int c = g >> 6;                           // chain id: 0..B_*D_-1
    int d = c & (D_ - 1);
    int b = c >> 10;
    int idx = (b * SEG_ + s) * D_ + d;
    float v = seg_sum[idx];
    float wp = 0.0343368382f;                 // 0.9^32 (per-segment decay)
#pragma unroll
    for (int off = 1; off < SEG_; off <<= 1) {
        float u = __shfl_up(v, off, 64);
        if (s >= off) v += wp * u;
        wp *= wp;                             // w^1, w^2, w^4, ...
    }
    float pv = __shfl_up(v, 1, 64);
    start_state[idx] = (s == 0) ? 0.f : pv;
}

// ---------------------------------------------------------------------------
// KC: recompute segment-local EMA seeded with start_state; emit fp8 (x8)
// into the packed operand layout.
__global__ __launch_bounds__(256)
void kC_ema_fp8(const float* __restrict__ spikes,
                const float* __restrict__ start_state,
                unsigned char* __restrict__ a_f8) {
    int t = blockIdx.x * 256 + threadIdx.x;            // B_*SEG_*D_/4 threads
    int dg = t & (D_ / 4 - 1);
    int s = (t >> 8) & (SEG_ - 1);
    int b = t >> 14;
    const float4* sp4 = (const float4*)spikes;
    const int base = (b * T_ + s * L_) * (D_ / 4) + dg;
    const int d0 = dg * 4;
    unsigned char* dst = a_f8 + pk_off(b * T_ + s * L_, d0);   // k=0 element
    float4 e = ((const float4*)start_state)[(b * SEG_ + s) * (D_ / 4) + dg];
#pragma unroll 8
    for (int k = 0; k < L_; ++k) {
        float4 x = sp4[base + k * (D_ / 4)];
        e.x = DECAYF * e.x + OMDF * x.x;
        e.y = DECAYF * e.y + OMDF * x.y;
        e.z = DECAYF * e.z + OMDF * x.z;
        e.w = DECAYF * e.w + OMDF * x.w;
        *(int*)(dst + k * 16) = pk_fp8x4(8.f*e.x, 8.f*e.y, 8.f*e.z, 8.f*e.w);
    }
}

// ---------------------------------------------------------------------------
// K2: MX-fp8 32x32x64 streaming GEMM, NO LDS. R5 synthesis of R1+R4:
//   R1 (no barrier):        44 us, FETCH 53 MB — pipelined but 2x redundant
//                           L2 reads (1 GB / ~23 TB/s == the 44 us).
//   R4 (__syncthreads):     69 us, FETCH 16 MB — dedupe PROVEN, but hipcc's
//                           implicit s_waitcnt vmcnt(0) before s_barrier
//                           drained the pipe 16x per block.
// R5: keep the lockstep, remove the drain:
//   - raw  asm("s_barrier")  — compiler doesn't know it's a barrier, so NO
//     vmcnt(0) drain is inserted; loads stay in flight across it. There is
//     no LDS in this kernel, so no correctness need for the drain.
//   - 2-stage register prefetch with sched_barrier(0) fences:
//     [barrier | fence | issue loads(C+1) | fence | MFMA(C)]
//     The fences stop the R1 failure (scheduler sinking loads into their
//     consumers) and the rule-#18 hazard (MFMA hoisting above waits). The
//     compiler's own dependency waitcnt before MFMA(C) is vmcnt(8) — a
//     counted wait (8 newest = loads(C+1) still outstanding), never a drain.
// Waves stay within one chunk window -> both readers of each tile arrive
// within ~16 KB of L1 footprint -> L1 dedupes -> L2 traffic ~halves.
// Falsifier: k2 >= 44 us with FETCH ~16 MB => lockstep tax > dedupe gain =>
// abandon barrier approaches for good.
// NOTE: plain __launch_bounds__(256). Never floor-cap this kernel (R5-old
// spilled at (256,3)); acc[2][2] only (acc[2][4] spilled in R3).
__global__ __launch_bounds__(256)
void k2_mfma_flags(const unsigned char* __restrict__ Ap,  // packed a_f8
                   const unsigned char* __restrict__ Bp,  // packed w_f8
                   unsigned int* __restrict__ flags) {
    const int tid = threadIdx.x;
    const int w = tid >> 6;
    const int lane = tid & 63;
    // XCD-chunked swizzle: 2048 blocks, 8 XCDs, 256 blocks/XCD as 16m x 16n.
    // Bijective since 2048 % 8 == 0. n-fast: consecutive blocks share the
    // A-panel (and may share a CU -> L1 A-dedupe across blocks too).
    const int orig = blockIdx.x;
    const int xcd  = orig & 7;
    const int id   = orig >> 3;            // 0..255 within XCD
    const int mt   = (xcd >> 1) * 16 + (id >> 4);   // 0..63 (m-tile)
    const int nt   = (xcd & 1) * 16 + (id & 15);    // 0..31 (n-tile, fast)
    const int m0 = mt * 128;
    const int n0 = nt * 128;
    const int wm = w >> 1, wn = w & 1;
    const int kg = lane >> 5;

    // Per-lane stream base pointers: 4 operand streams (2 A tiles, 2 B tiles).
    // Panel P's 16 k-tiles are contiguous (32 KB); chunk C reads at +C*2048.
    const unsigned char* pa0 = Ap + ((size_t)((m0 >> 5) + wm * 2 + 0) * 16) * 2048 + lane * 16;
    const unsigned char* pa1 = Ap + ((size_t)((m0 >> 5) + wm * 2 + 1) * 16) * 2048 + lane * 16;
    const unsigned char* pb0 = Bp + ((size_t)((n0 >> 5) + wn * 2 + 0) * 16) * 2048 + lane * 16;
    const unsigned char* pb1 = Bp + ((size_t)((n0 >> 5) + wn * 2 + 1) * 16) * 2048 + lane * 16;

    f32x16 acc[2][2] = {};

#define LDFRAG(p, C)                                                        \
    ({ i32x4 lo_ = *(const i32x4*)((p) + (size_t)(C) * 2048);               \
       i32x4 hi_ = *(const i32x4*)((p) + (size_t)(C) * 2048 + 1024);        \
       (i32x8){lo_.x, lo_.y, lo_.z, lo_.w, hi_.x, hi_.y, hi_.z, hi_.w}; })

#define MFMA4(AF0, AF1, BF0, BF1)                                           \
    {                                                                       \
        acc[0][0] = __builtin_amdgcn_mfma_scale_f32_32x32x64_f8f6f4(        \
            AF0, BF0, acc[0][0], 0, 0, 0, 124, 0, 124);                     \
        acc[0][1] = __builtin_amdgcn_mfma_scale_f32_32x32x64_f8f6f4(        \
            AF0, BF1, acc[0][1], 0, 0, 0, 124, 0, 124);                     \
        acc[1][0] = __builtin_amdgcn_mfma_scale_f32_32x32x64_f8f6f4(        \
            AF1, BF0, acc[1][0], 0, 0, 0, 124, 0, 124);                     \
        acc[1][1] = __builtin_amdgcn_mfma_scale_f32_32x32x64_f8f6f4(        \
            AF1, BF1, acc[1][1], 0, 0, 0, 124, 0, 124);                     \
    }

    // Two named stage sets (e/o) alternate across fully-unrolled chunks —
    // no register copies, no runtime stage index (rule #20).
    i32x8 A0e, A1e, B0e, B1e, A0o, A1o, B0o, B1o;
    A0e = LDFRAG(pa0, 0); A1e = LDFRAG(pa1, 0);
    B0e = LDFRAG(pb0, 0); B1e = LDFRAG(pb1, 0);

#define CHUNK(C, CUR, NXT)                                                  \
    asm volatile("s_barrier" ::: "memory");                                 \
    __builtin_amdgcn_sched_barrier(0);                                      \
    if ((C) < 15) {                                                         \
        A0##NXT = LDFRAG(pa0, (C) + 1); A1##NXT = LDFRAG(pa1, (C) + 1);     \
        B0##NXT = LDFRAG(pb0, (C) + 1); B1##NXT = LDFRAG(pb1, (C) + 1);     \
    }                                                                       \
    __builtin_amdgcn_sched_barrier(0);                                      \
    MFMA4(A0##CUR, A1##CUR, B0##CUR, B1##CUR);

    CHUNK(0,  e, o) CHUNK(1,  o, e) CHUNK(2,  e, o) CHUNK(3,  o, e)
    CHUNK(4,  e, o) CHUNK(5,  o, e) CHUNK(6,  e, o) CHUNK(7,  o, e)
    CHUNK(8,  e, o) CHUNK(9,  o, e) CHUNK(10, e, o) CHUNK(11, o, e)
    CHUNK(12, e, o) CHUNK(13, o, e) CHUNK(14, e, o) CHUNK(15, o, e)

#undef LDFRAG
#undef MFMA4
#undef CHUNK

    // Epilogue: per-row spike flags. 32x32 C/D layout (m74/m101-verified):
    // col = lane&31, row = (reg&3) + 8*(reg>>2) + 4*(lane>>5).
#pragma unroll
    for (int i = 0; i < 2; ++i) {
#pragma unroll
        for (int reg = 0; reg < 16; ++reg) {
            float mx = fmaxf(acc[i][0][reg], acc[i][1][reg]);
            if (mx > FLAG_THRESH) {
                const int rr = (reg & 3) + 8 * (reg >> 2) + 4 * kg;
                atomicOr(&flags[m0 + wm * 64 + i * 32 + rr], 1u);
            }
        }
    }
}

// ---------------------------------------------------------------------------
// K4: one block per (b,t) row. Unflagged rows (the overwhelmingly common
// case) write zeros. Flagged rows take the exact fp32 slow path, rebuilding
// the EMA row from start_state + <=32 spike rows.
__global__ __launch_bounds__(256)
void k4_output(const float* __restrict__ spikes,
               const float* __restrict__ start_state,
               const float* __restrict__ W1,
               const float* __restrict__ Wr,
               const float* __restrict__ W2,
               const unsigned int* __restrict__ flags,
               float* __restrict__ out) {
    const int row = blockIdx.x;          // 0..R_-1
    const int tid = threadIdx.x;
    float4 o = {0.f, 0.f, 0.f, 0.f};

    if (flags[row] == 0u) {              // wave-uniform branch (per block)
        *(float4*)&out[(size_t)row * D_ + tid * 4] = o;
        return;
    }

    __shared__ float se[D_];
    __shared__ float sp[D_];
    __shared__ float red[256];
    __shared__ int nspk;
    __shared__ int spk_list[256];

    const int b = row / T_;
    const int t = row % T_;
    const int seg = t / L_;
    const int off = t % L_;
    const int segbase = (b * T_ + seg * L_) * D_;

    for (int i = tid; i < D_; i += 256) {
        float e = start_state[(b * SEG_ + seg) * D_ + i];
        for (int j = 0; j <= off; ++j)
            e = DECAYF * e + OMDF * spikes[segbase + j * D_ + i];
        se[i] = e;
        sp[i] = spikes[(size_t)row * D_ + i];
    }
    if (tid == 0) nspk = 0;
    __syncthreads();

    for (int f0 = 0; f0 < F_; f0 += 256) {
        int f = f0 + tid;
        float mix = 0.f;
        for (int k = 0; k < D_; ++k) mix += se[k] * W1[(size_t)f * D_ + k];
        if (mix > 0.5f) {
            int idx = atomicAdd(&nspk, 1);
            spk_list[idx] = f;
        }
        __syncthreads();
        int n = nspk;
        for (int i = 0; i < n; ++i) {
            int fs = spk_list[i];
            float part = 0.f;
#pragma unroll
            for (int k = 0; k < 4; ++k)
                part += sp[tid * 4 + k] * Wr[(size_t)fs * D_ + tid * 4 + k];
            red[tid] = part;
            __syncthreads();
            for (int sft = 128; sft > 0; sft >>= 1) {
                if (tid < sft) red[tid] += red[tid + sft];
                __syncthreads();
            }
            float r = 1.f / (1.f + expf(-red[0]));
            __syncthreads();
            o.x += r * W2[(size_t)(tid * 4 + 0) * F_ + fs];
            o.y += r * W2[(size_t)(tid * 4 + 1) * F_ + fs];
            o.z += r * W2[(size_t)(tid * 4 + 2) * F_ + fs];
            o.w += r * W2[(size_t)(tid * 4 + 3) * F_ + fs];
        }
        __syncthreads();
        if (tid == 0) nspk = 0;
        __syncthreads();
    }
    *(float4*)&out[(size_t)row * D_ + tid * 4] = o;
}

// ---------------------------------------------------------------------------
extern "C" void kernel_launch(void* const* d_in, const int* in_sizes, int n_in,
                              void* d_out, int out_size, void* d_ws, size_t ws_size,
                              hipStream_t stream) {
    const float* spikes = (const float*)d_in[0];   // [B,T,D]
    const float* W1     = (const float*)d_in[1];   // [F,D]
    const float* W2     = (const float*)d_in[2];   // [D,F]
    const float* Wr     = (const float*)d_in[3];   // [F,D]
    float* out = (float*)d_out;                    // [B,T,D]

    // workspace layout (~14.3 MB total)
    char* ws = (char*)d_ws;
    float* seg_sum      = (float*)ws;                                // 1 MB
    float* start_state  = seg_sum + (size_t)B_ * SEG_ * D_;          // 1 MB
    unsigned int* flags = (unsigned int*)(start_state + (size_t)B_ * SEG_ * D_); // 32 KB
    unsigned char* a_f8 = (unsigned char*)(flags + R_);              // 8 MB, packed
    unsigned char* w_f8 = a_f8 + (size_t)R_ * D_;                    // 4 MB, packed

    kA_prologue<<<KA_W1_BLOCKS + KA_SEG_BLOCKS + KA_FLAG_BLOCKS, 256, 0, stream>>>(
        spikes, W1, w_f8, seg_sum, flags);
    kB_seg_scan<<<(B_ * D_ * 64) / 256, 256, 0, stream>>>(seg_sum, start_state);
    kC_ema_fp8<<<(B_ * SEG_ * D_ / 4) / 256, 256, 0, stream>>>(spikes, start_state, a_f8);

    k2_mfma_flags<<<(R_ / 128) * (F_ / 128), 256, 0, stream>>>(a_f8, w_f8, flags);

    k4_output<<<R_, 256, 0, stream>>>(spikes, start_state, W1, Wr, W2, flags, out);
}